// Round 4
// baseline (241.335 us; speedup 1.0000x reference)
//
#include <hip/hip_runtime.h>

typedef unsigned short ushort_t;
typedef unsigned int uint_t;
typedef __attribute__((ext_vector_type(8))) short short8;
typedef __attribute__((ext_vector_type(4))) float floatx4;

#define QSCALE 0.03187936f  // (1/sqrt(2048)) * log2(e): quirk scale + exp2 fold

__device__ __forceinline__ ushort_t f2bf(float f) {
    union { float f; uint_t u; } c; c.f = f;
    uint_t u = c.u;
    return (ushort_t)((u + 0x7fffu + ((u >> 16) & 1u)) >> 16);  // RNE
}
__device__ __forceinline__ floatx4 mfma16x32(short8 a, short8 b, floatx4 c) {
    return __builtin_amdgcn_mfma_f32_16x16x32_bf16(a, b, c, 0, 0, 0);
}
__device__ __forceinline__ floatx4 zero4() { floatx4 z = {0.f, 0.f, 0.f, 0.f}; return z; }

// Async 16B global->LDS. Per-lane lds ptr = base + lane*16B slot (HW uses
// lane0's ptr as wave base and strides lane*16 — matches our linear slots).
__device__ __forceinline__ void gload16(const ushort_t* g, ushort_t* l) {
    __builtin_amdgcn_global_load_lds(
        (const __attribute__((address_space(1))) void*)g,
        (__attribute__((address_space(3))) void*)l, 16, 0, 0);
}

// ---------------------------------------------------------------------------
// f32 -> bf16 convert (RNE), 8 elems/thread, up to 3 tensors of 4M elems.
// ---------------------------------------------------------------------------
__global__ __launch_bounds__(256) void cvt_bf16(
    const float* __restrict__ s0, const float* __restrict__ s1,
    const float* __restrict__ s2, ushort_t* __restrict__ d0,
    ushort_t* __restrict__ d1, ushort_t* __restrict__ d2)
{
    const int which = blockIdx.x >> 11;
    const int blk = blockIdx.x & 2047;
    const float* src = (which == 0) ? s0 : (which == 1) ? s1 : s2;
    ushort_t* dst = (which == 0) ? d0 : (which == 1) ? d1 : d2;
    const int i = (blk * 256 + threadIdx.x) * 8;
    float4 f0 = *(const float4*)(src + i);
    float4 f1 = *(const float4*)(src + i + 4);
    __align__(16) ushort_t t[8];
    t[0] = f2bf(f0.x); t[1] = f2bf(f0.y); t[2] = f2bf(f0.z); t[3] = f2bf(f0.w);
    t[4] = f2bf(f1.x); t[5] = f2bf(f1.y); t[6] = f2bf(f1.z); t[7] = f2bf(f1.w);
    *(uint4*)(dst + i) = *(uint4*)t;
}

// ---------------------------------------------------------------------------
// Fused convert+transpose: W[k][j] (1024x1024 f32) -> WT[j][k] bf16.
// ---------------------------------------------------------------------------
__global__ __launch_bounds__(256) void transpose_w(
    const float* __restrict__ W0, const float* __restrict__ W1,
    const float* __restrict__ W2, const float* __restrict__ W3,
    ushort_t* __restrict__ WT)
{
    __shared__ ushort_t tile[64][65];
    const float* W = (blockIdx.y == 0) ? W0 : (blockIdx.y == 1) ? W1
                   : (blockIdx.y == 2) ? W2 : W3;
    ushort_t* dst = WT + (size_t)blockIdx.y * (1024 * 1024);
    const int t = threadIdx.x;
    const int r = t >> 2, p = t & 3;
    const int j0 = (blockIdx.x & 15) << 6, k0 = (blockIdx.x >> 4) << 6;

    const float* src = W + (size_t)(k0 + r) * 1024 + j0 + p * 16;
    float4 f0 = *(const float4*)(src);
    float4 f1 = *(const float4*)(src + 4);
    float4 f2 = *(const float4*)(src + 8);
    float4 f3 = *(const float4*)(src + 12);
    ushort_t* tr = &tile[r][p * 16];
    tr[0] = f2bf(f0.x); tr[1] = f2bf(f0.y); tr[2]  = f2bf(f0.z); tr[3]  = f2bf(f0.w);
    tr[4] = f2bf(f1.x); tr[5] = f2bf(f1.y); tr[6]  = f2bf(f1.z); tr[7]  = f2bf(f1.w);
    tr[8] = f2bf(f2.x); tr[9] = f2bf(f2.y); tr[10] = f2bf(f2.z); tr[11] = f2bf(f2.w);
    tr[12] = f2bf(f3.x); tr[13] = f2bf(f3.y); tr[14] = f2bf(f3.z); tr[15] = f2bf(f3.w);
    __syncthreads();
    __align__(16) ushort_t buf[16];
#pragma unroll
    for (int i = 0; i < 16; ++i) buf[i] = tile[p * 16 + i][r];
    ushort_t* o = dst + (size_t)(j0 + r) * 1024 + k0 + p * 16;
    *(uint4*)(o)     = *(uint4*)(buf);
    *(uint4*)(o + 8) = *(uint4*)(buf + 8);
}

// ---------------------------------------------------------------------------
// Projection GEMM: C[r][c] = sum_k A[r][k]*WT[c][k] + bias[c]. 4096x1024x1024.
// 128x128 tile, BK=32, global_load_lds staging, XOR-swizzled LDS chunks.
// mode = blockIdx.z + zbase: 0: Q -> [B,H,S,64] *QSCALE; 1: K -> [B,H,S,64];
// 2: V -> [B,H,64,S].
// ---------------------------------------------------------------------------
__global__ __launch_bounds__(256) void gemm_bt(
    const ushort_t* __restrict__ A0, const ushort_t* __restrict__ A1,
    const ushort_t* __restrict__ A2, const ushort_t* __restrict__ WT,
    const float* __restrict__ b0, const float* __restrict__ b1,
    const float* __restrict__ b2,
    ushort_t* __restrict__ Dq, ushort_t* __restrict__ Dk,
    ushort_t* __restrict__ Dv, int zbase)
{
    __shared__ __align__(16) ushort_t As[128 * 32];
    __shared__ __align__(16) ushort_t Bs[128 * 32];

    const int mode = blockIdx.z + zbase;
    const ushort_t* A = (mode == 0) ? A0 : (mode == 1) ? A1 : A2;
    const float* bias = (mode == 0) ? b0 : (mode == 1) ? b1 : b2;
    const ushort_t* Bt = WT + (size_t)mode * 1048576;

    const int tid = threadIdx.x;
    const int lane = tid & 63, wid = tid >> 6;
    const int quad = lane >> 4, l16 = lane & 15;
    const int wm = wid >> 1, wn = wid & 1;
    const int row0 = blockIdx.y << 7, col0 = blockIdx.x << 7;

    floatx4 acc[4][4];
#pragma unroll
    for (int i = 0; i < 4; ++i)
#pragma unroll
        for (int j = 0; j < 4; ++j) acc[i][j] = zero4();

    const int i0 = tid, i1 = 256 + tid;
    const int r0_ = i0 >> 2, c0_ = (i0 & 3) ^ (r0_ & 3);
    const int r1_ = i1 >> 2, c1_ = (i1 & 3) ^ (r1_ & 3);
    const ushort_t* gA0 = A  + (size_t)(row0 + r0_) * 1024 + c0_ * 8;
    const ushort_t* gA1 = A  + (size_t)(row0 + r1_) * 1024 + c1_ * 8;
    const ushort_t* gB0 = Bt + (size_t)(col0 + r0_) * 1024 + c0_ * 8;
    const ushort_t* gB1 = Bt + (size_t)(col0 + r1_) * 1024 + c1_ * 8;
    ushort_t* lA0 = As + i0 * 8;  ushort_t* lA1 = As + i1 * 8;
    ushort_t* lB0 = Bs + i0 * 8;  ushort_t* lB1 = Bs + i1 * 8;

    const int ra = wm * 64 + l16, rb = wn * 64 + l16;
    const int sa_off = (quad ^ (l16 & 3)) * 8;

    for (int k0 = 0; k0 < 1024; k0 += 32) {
        __syncthreads();
        gload16(gA0 + k0, lA0);
        gload16(gA1 + k0, lA1);
        gload16(gB0 + k0, lB0);
        gload16(gB1 + k0, lB1);
        __syncthreads();

        short8 af[4], bf[4];
#pragma unroll
        for (int i = 0; i < 4; ++i)
            af[i] = *(const short8*)(As + (ra + i * 16) * 32 + sa_off);
#pragma unroll
        for (int j = 0; j < 4; ++j)
            bf[j] = *(const short8*)(Bs + (rb + j * 16) * 32 + sa_off);
#pragma unroll
        for (int i = 0; i < 4; ++i)
#pragma unroll
            for (int j = 0; j < 4; ++j)
                acc[i][j] = mfma16x32(af[i], bf[j], acc[i][j]);
    }

    const float sc = (mode == 0) ? QSCALE : 1.f;
#pragma unroll
    for (int i = 0; i < 4; ++i) {
#pragma unroll
        for (int j = 0; j < 4; ++j) {
            const int c = col0 + wn * 64 + j * 16 + l16;
            const float bv = bias[c];
#pragma unroll
            for (int rr = 0; rr < 4; ++rr) {
                const int r = row0 + wm * 64 + i * 16 + quad * 4 + rr;
                const float v = (acc[i][j][rr] + bv) * sc;
                const int b = r >> 11, s = r & 2047, h = c >> 6, d = c & 63;
                if (mode <= 1) {
                    ushort_t* D = (mode == 0) ? Dq : Dk;
                    D[(((b * 16 + h) * 2048 + s) << 6) + d] = f2bf(v);
                } else {
                    Dv[(((b * 16 + h) * 64 + d) << 11) + s] = f2bf(v);
                }
            }
        }
    }
}

// ---------------------------------------------------------------------------
// Output GEMM: Dout[r][c] = sum_k A[r][k]*WoT[c][k] + bias[c], f32 out.
// 64x128 tile -> 512 blocks (2 blocks/CU).
// ---------------------------------------------------------------------------
__global__ __launch_bounds__(256) void gemm64(
    const ushort_t* __restrict__ A, const ushort_t* __restrict__ Bt,
    const float* __restrict__ bias, float* __restrict__ Dout)
{
    __shared__ __align__(16) ushort_t As[64 * 32];
    __shared__ __align__(16) ushort_t Bs[128 * 32];
    const int tid = threadIdx.x;
    const int lane = tid & 63, wid = tid >> 6;
    const int quad = lane >> 4, l16 = lane & 15;
    const int wm = wid >> 1, wn = wid & 1;
    const int row0 = blockIdx.y << 6, col0 = blockIdx.x << 7;

    floatx4 acc[2][4];
#pragma unroll
    for (int i = 0; i < 2; ++i)
#pragma unroll
        for (int j = 0; j < 4; ++j) acc[i][j] = zero4();

    const int rA = tid >> 2, cA = (tid & 3) ^ (rA & 3);
    const ushort_t* gA = A + (size_t)(row0 + rA) * 1024 + cA * 8;
    ushort_t* lA = As + tid * 8;
    const int i0 = tid, i1 = 256 + tid;
    const int rB0 = i0 >> 2, cB0 = (i0 & 3) ^ (rB0 & 3);
    const int rB1 = i1 >> 2, cB1 = (i1 & 3) ^ (rB1 & 3);
    const ushort_t* gB0 = Bt + (size_t)(col0 + rB0) * 1024 + cB0 * 8;
    const ushort_t* gB1 = Bt + (size_t)(col0 + rB1) * 1024 + cB1 * 8;
    ushort_t* lB0 = Bs + i0 * 8;  ushort_t* lB1 = Bs + i1 * 8;

    const int sa_off = (quad ^ (l16 & 3)) * 8;

    for (int k0 = 0; k0 < 1024; k0 += 32) {
        __syncthreads();
        gload16(gA + k0, lA);
        gload16(gB0 + k0, lB0);
        gload16(gB1 + k0, lB1);
        __syncthreads();

        short8 af[2], bf[4];
#pragma unroll
        for (int i = 0; i < 2; ++i)
            af[i] = *(const short8*)(As + (wm * 32 + i * 16 + l16) * 32 + sa_off);
#pragma unroll
        for (int j = 0; j < 4; ++j)
            bf[j] = *(const short8*)(Bs + (wn * 64 + j * 16 + l16) * 32 + sa_off);
#pragma unroll
        for (int i = 0; i < 2; ++i)
#pragma unroll
            for (int j = 0; j < 4; ++j)
                acc[i][j] = mfma16x32(af[i], bf[j], acc[i][j]);
    }

#pragma unroll
    for (int i = 0; i < 2; ++i)
#pragma unroll
        for (int j = 0; j < 4; ++j) {
            const int c = col0 + wn * 64 + j * 16 + l16;
            const float bv = bias[c];
#pragma unroll
            for (int rr = 0; rr < 4; ++rr) {
                const int r = row0 + wm * 32 + i * 16 + quad * 4 + rr;
                Dout[(size_t)r * 1024 + c] = acc[i][j][rr] + bv;
            }
        }
}

// ---------------------------------------------------------------------------
// Attention, q-subtile reuse restructure of the VERIFIED attn64 body.
// Grid 1024 = 32 bh (head-major, XCD = blk%8) x 32 q-tiles of 64 rows;
// 2 waves x 32 q-rows (two 16-row MFMA subtiles u=0,1) per block.
// Per 64-kcol tile: K-frags (QK^T A-operand) and V-frags (PV B-operand) are
// q-independent -> read from LDS ONCE, consumed by BOTH subtiles: LDS-read
// bytes per unit work HALVED vs attn64 (the R0-diagnosed bottleneck).
// All fragment maps, softmax pack (truncated bf16 + truncated-sum denom),
// swizzle, staging, and epilogue are copied verbatim from passing attn64;
// only addressing (wid*32 + u*16) and loop structure changed.
// ---------------------------------------------------------------------------
__global__ __launch_bounds__(128, 2) void attn64q(
    const ushort_t* __restrict__ Q, const ushort_t* __restrict__ K,
    const ushort_t* __restrict__ Vt, ushort_t* __restrict__ Out)
{
    __shared__ __align__(16) ushort_t Ks[64 * 64];  // [kcol][d], swizzled chunks
    __shared__ __align__(16) ushort_t Vs[64 * 64];  // [d][kcol], swizzled chunks

    const int tid = threadIdx.x;
    const int lane = tid & 63, wid = tid >> 6;   // 2 waves
    const int quad = lane >> 4, l16 = lane & 15;
    const int blk = blockIdx.x;
    const int bh = blk & 31;          // head-major: XCD = blk%8 = bh%8
    const int q0 = (blk >> 5) << 6;   // 64 q-rows per block

    const ushort_t* Qh = Q + (size_t)bh * (2048 * 64);
    const ushort_t* Kh = K + (size_t)bh * (2048 * 64);
    const ushort_t* Vh = Vt + (size_t)bh * (64 * 2048);

    // Q fragments for both subtiles (B-operand: n=qrow=l16, k=8*quad+j)
    short8 qf0[2], qf1[2];
#pragma unroll
    for (int u = 0; u < 2; ++u) {
        const int qr = q0 + wid * 32 + u * 16 + l16;
        qf0[u] = *(const short8*)(Qh + (size_t)qr * 64 + quad * 8);
        qf1[u] = *(const short8*)(Qh + (size_t)qr * 64 + 32 + quad * 8);
    }

    float l_st[2] = {0.f, 0.f};
    floatx4 o_acc[2][4];
#pragma unroll
    for (int u = 0; u < 2; ++u)
#pragma unroll
        for (int d = 0; d < 4; ++d) o_acc[u][d] = zero4();

    // staging: 4 slots per thread per tensor (128 thr x 4 = 512 slots).
    // kc is i-invariant: ((tid+128i)&7)^(((tid+128i)>>3)&7) = (tid&7)^(kr&7).
    const int kr = tid >> 3, kc = (tid & 7) ^ (kr & 7);
    const ushort_t* gK0 = Kh + (size_t)kr * 64 + kc * 8;
    const ushort_t* gV0 = Vh + (size_t)kr * 2048 + kc * 8;
    ushort_t* lK0 = Ks + tid * 8;
    ushort_t* lV0 = Vs + tid * 8;

    const int l7 = l16 & 7;
    const int q2 = quad >> 1, q1 = (quad & 1) * 4;

    for (int kt = 0; kt < 2048; kt += 64) {
        __syncthreads();
#pragma unroll
        for (int i = 0; i < 4; ++i) {
            gload16(gK0 + (size_t)kt * 64 + i * 1024, lK0 + i * 1024);
            gload16(gV0 + kt + (size_t)i * 32768, lV0 + i * 1024);
        }
        __syncthreads();

        // S^T tiles: A = K-frag (m=kcol) read ONCE, B = Q-frag per subtile
        floatx4 sa[2][4];
#pragma unroll
        for (int g = 0; g < 4; ++g) {
            const int row = g * 16 + l16;  // kcol
            const short8 kf0 = *(const short8*)(Ks + row * 64 + ((quad ^ l7) * 8));
            const short8 kf1 = *(const short8*)(Ks + row * 64 + (((quad + 4) ^ l7) * 8));
#pragma unroll
            for (int u = 0; u < 2; ++u) {
                floatx4 t0 = mfma16x32(kf0, qf0[u], zero4());
                sa[u][g] = mfma16x32(kf1, qf1[u], t0);
            }
        }

        // softmax + pack two g-blocks per K=32 PV MFMA; V-frags shared by subtiles
#pragma unroll
        for (int G = 0; G < 2; ++G) {
            short8 pf[2];
#pragma unroll
            for (int u = 0; u < 2; ++u) {
                uint_t ub[8];
#pragma unroll
                for (int t = 0; t < 8; ++t) {
                    const int g = G * 2 + (t >> 2), r = t & 3;
                    const float e = __builtin_amdgcn_exp2f(fminf(sa[u][g][r], 80.f));
                    const uint_t uu = __float_as_uint(e) & 0xffff0000u;
                    l_st[u] += __uint_as_float(uu);   // sum the TRUNCATED value
                    ub[t] = uu;
                }
                union { uint_t u4[4]; short8 s; } pc;
                pc.u4[0] = (ub[0] >> 16) | ub[1];
                pc.u4[1] = (ub[2] >> 16) | ub[3];
                pc.u4[2] = (ub[4] >> 16) | ub[5];
                pc.u4[3] = (ub[6] >> 16) | ub[7];
                pf[u] = pc.s;
            }
            const int ch0 = ((4 * G + q2) ^ l7) * 8;
            const int ch1 = ((4 * G + 2 + q2) ^ l7) * 8;
#pragma unroll
            for (int db = 0; db < 4; ++db) {
                const int vbase = (db * 16 + l16) * 64 + q1;
                const uint2 v0 = *(const uint2*)(Vs + vbase + ch0);
                const uint2 v1 = *(const uint2*)(Vs + vbase + ch1);
                union { uint_t u4[4]; short8 s; } vc;
                vc.u4[0] = v0.x; vc.u4[1] = v0.y; vc.u4[2] = v1.x; vc.u4[3] = v1.y;
                o_acc[0][db] = mfma16x32(pf[0], vc.s, o_acc[0][db]);
                o_acc[1][db] = mfma16x32(pf[1], vc.s, o_acc[1][db]);
            }
        }
    }

    // denominator + write per subtile (exact attn64 epilogue, s0 shifted)
    const int b = bh >> 4, hh = bh & 15;
#pragma unroll
    for (int u = 0; u < 2; ++u) {
        float l = l_st[u];
        l += __shfl_xor(l, 16);
        l += __shfl_xor(l, 32);
        const int s0 = q0 + wid * 32 + u * 16 + quad * 4;
#pragma unroll
        for (int r = 0; r < 4; ++r) {
            const float lr = __shfl(l, quad * 4 + r);  // l of qrow quad*4+r
            const float inv = 1.f / lr;
#pragma unroll
            for (int db = 0; db < 4; ++db) {
                const float v = o_acc[u][db][r] * inv;
                Out[(size_t)(b * 2048 + s0 + r) * 1024 + hh * 64 + db * 16 + l16] = f2bf(v);
            }
        }
    }
}

// ---------------------------------------------------------------------------
// Launch (attn grid 1024 = 32 bh x 32 q-tiles of 64 rows, 128 threads).
//  big (>=64MiB): WT@0 Qb@8M Kb@16M Vb@24M Qp@32M Kp@40M Vtp@48M An@56M
//  small (40MiB): WT@0 buf1@8M buf2@16M Qp@24M Kp@32M
// ---------------------------------------------------------------------------
extern "C" void kernel_launch(void* const* d_in, const int* in_sizes, int n_in,
                              void* d_out, int out_size, void* d_ws, size_t ws_size,
                              hipStream_t stream) {
    const float* queries = (const float*)d_in[0];
    const float* keys    = (const float*)d_in[1];
    const float* values  = (const float*)d_in[2];
    const float* Wq = (const float*)d_in[3];
    const float* bq = (const float*)d_in[4];
    const float* Wk = (const float*)d_in[5];
    const float* bk = (const float*)d_in[6];
    const float* Wv = (const float*)d_in[7];
    const float* bv = (const float*)d_in[8];
    const float* Wo = (const float*)d_in[9];
    const float* bo = (const float*)d_in[10];
    float* out = (float*)d_out;

    char* ws = (char*)d_ws;
    const size_t MB = 1024 * 1024;
    ushort_t* WT = (ushort_t*)(ws);
    const ushort_t* WoT = WT + 3 * 1048576;
    dim3 tb(256);
    dim3 ta(128);

    transpose_w<<<dim3(256, 4), tb, 0, stream>>>(Wq, Wk, Wv, Wo, WT);

    if (ws_size >= 64 * MB) {
        ushort_t* Qb  = (ushort_t*)(ws + 8 * MB);
        ushort_t* Kb  = (ushort_t*)(ws + 16 * MB);
        ushort_t* Vb  = (ushort_t*)(ws + 24 * MB);
        ushort_t* Qp  = (ushort_t*)(ws + 32 * MB);
        ushort_t* Kp  = (ushort_t*)(ws + 40 * MB);
        ushort_t* Vtp = (ushort_t*)(ws + 48 * MB);
        ushort_t* An  = (ushort_t*)(ws + 56 * MB);
        cvt_bf16<<<dim3(6144), tb, 0, stream>>>(queries, keys, values, Qb, Kb, Vb);
        gemm_bt<<<dim3(8, 32, 3), tb, 0, stream>>>(Qb, Kb, Vb, WT,
            bq, bk, bv, Qp, Kp, Vtp, 0);
        attn64q<<<dim3(1024), ta, 0, stream>>>(Qp, Kp, Vtp, An);
        gemm64<<<dim3(8, 64), tb, 0, stream>>>(An, WoT, bo, out);
    } else {
        ushort_t* buf1 = (ushort_t*)(ws + 8 * MB);
        ushort_t* buf2 = (ushort_t*)(ws + 16 * MB);
        ushort_t* Qp   = (ushort_t*)(ws + 24 * MB);
        ushort_t* Kp   = (ushort_t*)(ws + 32 * MB);
        cvt_bf16<<<dim3(4096), tb, 0, stream>>>(queries, keys, keys, buf1, buf2, buf2);
        gemm_bt<<<dim3(8, 32, 2), tb, 0, stream>>>(buf1, buf2, buf2, WT,
            bq, bk, bk, Qp, Kp, Kp, 0);
        cvt_bf16<<<dim3(2048), tb, 0, stream>>>(values, values, values, buf1, buf1, buf1);
        gemm_bt<<<dim3(8, 32, 1), tb, 0, stream>>>(buf1, buf1, buf1, WT,
            bv, bv, bv, buf2, buf2, buf2, 2);   // mode 2: V -> Vtp = buf2
        attn64q<<<dim3(1024), ta, 0, stream>>>(Qp, Kp, buf2, buf1);
        gemm64<<<dim3(8, 64), tb, 0, stream>>>(buf1, WoT, bo, out);
    }
}

// Round 5
// 230.591 us; speedup vs baseline: 1.0466x; 1.0466x over previous
//
#include <hip/hip_runtime.h>

typedef unsigned short ushort_t;
typedef unsigned int uint_t;
typedef __attribute__((ext_vector_type(8))) short short8;
typedef __attribute__((ext_vector_type(4))) float floatx4;

#define QSCALE 0.03187936f  // (1/sqrt(2048)) * log2(e): quirk scale + exp2 fold

__device__ __forceinline__ ushort_t f2bf(float f) {
    union { float f; uint_t u; } c; c.f = f;
    uint_t u = c.u;
    return (ushort_t)((u + 0x7fffu + ((u >> 16) & 1u)) >> 16);  // RNE
}
__device__ __forceinline__ floatx4 mfma16x32(short8 a, short8 b, floatx4 c) {
    return __builtin_amdgcn_mfma_f32_16x16x32_bf16(a, b, c, 0, 0, 0);
}
__device__ __forceinline__ floatx4 zero4() { floatx4 z = {0.f, 0.f, 0.f, 0.f}; return z; }

// Async 16B global->LDS. Per-lane lds ptr = base + lane*16B slot (HW uses
// lane0's ptr as wave base and strides lane*16 — matches our linear slots).
__device__ __forceinline__ void gload16(const ushort_t* g, ushort_t* l) {
    __builtin_amdgcn_global_load_lds(
        (const __attribute__((address_space(1))) void*)g,
        (__attribute__((address_space(3))) void*)l, 16, 0, 0);
}

// ---------------------------------------------------------------------------
// f32 -> bf16 convert (RNE), 8 elems/thread, up to 3 tensors of 4M elems.
// ---------------------------------------------------------------------------
__global__ __launch_bounds__(256) void cvt_bf16(
    const float* __restrict__ s0, const float* __restrict__ s1,
    const float* __restrict__ s2, ushort_t* __restrict__ d0,
    ushort_t* __restrict__ d1, ushort_t* __restrict__ d2)
{
    const int which = blockIdx.x >> 11;
    const int blk = blockIdx.x & 2047;
    const float* src = (which == 0) ? s0 : (which == 1) ? s1 : s2;
    ushort_t* dst = (which == 0) ? d0 : (which == 1) ? d1 : d2;
    const int i = (blk * 256 + threadIdx.x) * 8;
    float4 f0 = *(const float4*)(src + i);
    float4 f1 = *(const float4*)(src + i + 4);
    __align__(16) ushort_t t[8];
    t[0] = f2bf(f0.x); t[1] = f2bf(f0.y); t[2] = f2bf(f0.z); t[3] = f2bf(f0.w);
    t[4] = f2bf(f1.x); t[5] = f2bf(f1.y); t[6] = f2bf(f1.z); t[7] = f2bf(f1.w);
    *(uint4*)(dst + i) = *(uint4*)t;
}

// ---------------------------------------------------------------------------
// Fused convert+transpose: W[k][j] (1024x1024 f32) -> WT[j][k] bf16.
// ---------------------------------------------------------------------------
__global__ __launch_bounds__(256) void transpose_w(
    const float* __restrict__ W0, const float* __restrict__ W1,
    const float* __restrict__ W2, const float* __restrict__ W3,
    ushort_t* __restrict__ WT)
{
    __shared__ ushort_t tile[64][65];
    const float* W = (blockIdx.y == 0) ? W0 : (blockIdx.y == 1) ? W1
                   : (blockIdx.y == 2) ? W2 : W3;
    ushort_t* dst = WT + (size_t)blockIdx.y * (1024 * 1024);
    const int t = threadIdx.x;
    const int r = t >> 2, p = t & 3;
    const int j0 = (blockIdx.x & 15) << 6, k0 = (blockIdx.x >> 4) << 6;

    const float* src = W + (size_t)(k0 + r) * 1024 + j0 + p * 16;
    float4 f0 = *(const float4*)(src);
    float4 f1 = *(const float4*)(src + 4);
    float4 f2 = *(const float4*)(src + 8);
    float4 f3 = *(const float4*)(src + 12);
    ushort_t* tr = &tile[r][p * 16];
    tr[0] = f2bf(f0.x); tr[1] = f2bf(f0.y); tr[2]  = f2bf(f0.z); tr[3]  = f2bf(f0.w);
    tr[4] = f2bf(f1.x); tr[5] = f2bf(f1.y); tr[6]  = f2bf(f1.z); tr[7]  = f2bf(f1.w);
    tr[8] = f2bf(f2.x); tr[9] = f2bf(f2.y); tr[10] = f2bf(f2.z); tr[11] = f2bf(f2.w);
    tr[12] = f2bf(f3.x); tr[13] = f2bf(f3.y); tr[14] = f2bf(f3.z); tr[15] = f2bf(f3.w);
    __syncthreads();
    __align__(16) ushort_t buf[16];
#pragma unroll
    for (int i = 0; i < 16; ++i) buf[i] = tile[p * 16 + i][r];
    ushort_t* o = dst + (size_t)(j0 + r) * 1024 + k0 + p * 16;
    *(uint4*)(o)     = *(uint4*)(buf);
    *(uint4*)(o + 8) = *(uint4*)(buf + 8);
}

// ---------------------------------------------------------------------------
// Projection GEMM: C[r][c] = sum_k A[r][k]*WT[c][k] + bias[c]. 4096x1024x1024.
// 128x128 tile, BK=32, global_load_lds staging, XOR-swizzled LDS chunks.
// mode = blockIdx.z + zbase: 0: Q -> [B,H,S,64] *QSCALE; 1: K -> [B,H,S,64];
// 2: V -> [B,H,64,S].
// ---------------------------------------------------------------------------
__global__ __launch_bounds__(256) void gemm_bt(
    const ushort_t* __restrict__ A0, const ushort_t* __restrict__ A1,
    const ushort_t* __restrict__ A2, const ushort_t* __restrict__ WT,
    const float* __restrict__ b0, const float* __restrict__ b1,
    const float* __restrict__ b2,
    ushort_t* __restrict__ Dq, ushort_t* __restrict__ Dk,
    ushort_t* __restrict__ Dv, int zbase)
{
    __shared__ __align__(16) ushort_t As[128 * 32];
    __shared__ __align__(16) ushort_t Bs[128 * 32];

    const int mode = blockIdx.z + zbase;
    const ushort_t* A = (mode == 0) ? A0 : (mode == 1) ? A1 : A2;
    const float* bias = (mode == 0) ? b0 : (mode == 1) ? b1 : b2;
    const ushort_t* Bt = WT + (size_t)mode * 1048576;

    const int tid = threadIdx.x;
    const int lane = tid & 63, wid = tid >> 6;
    const int quad = lane >> 4, l16 = lane & 15;
    const int wm = wid >> 1, wn = wid & 1;
    const int row0 = blockIdx.y << 7, col0 = blockIdx.x << 7;

    floatx4 acc[4][4];
#pragma unroll
    for (int i = 0; i < 4; ++i)
#pragma unroll
        for (int j = 0; j < 4; ++j) acc[i][j] = zero4();

    const int i0 = tid, i1 = 256 + tid;
    const int r0_ = i0 >> 2, c0_ = (i0 & 3) ^ (r0_ & 3);
    const int r1_ = i1 >> 2, c1_ = (i1 & 3) ^ (r1_ & 3);
    const ushort_t* gA0 = A  + (size_t)(row0 + r0_) * 1024 + c0_ * 8;
    const ushort_t* gA1 = A  + (size_t)(row0 + r1_) * 1024 + c1_ * 8;
    const ushort_t* gB0 = Bt + (size_t)(col0 + r0_) * 1024 + c0_ * 8;
    const ushort_t* gB1 = Bt + (size_t)(col0 + r1_) * 1024 + c1_ * 8;
    ushort_t* lA0 = As + i0 * 8;  ushort_t* lA1 = As + i1 * 8;
    ushort_t* lB0 = Bs + i0 * 8;  ushort_t* lB1 = Bs + i1 * 8;

    const int ra = wm * 64 + l16, rb = wn * 64 + l16;
    const int sa_off = (quad ^ (l16 & 3)) * 8;

    for (int k0 = 0; k0 < 1024; k0 += 32) {
        __syncthreads();
        gload16(gA0 + k0, lA0);
        gload16(gA1 + k0, lA1);
        gload16(gB0 + k0, lB0);
        gload16(gB1 + k0, lB1);
        __syncthreads();

        short8 af[4], bf[4];
#pragma unroll
        for (int i = 0; i < 4; ++i)
            af[i] = *(const short8*)(As + (ra + i * 16) * 32 + sa_off);
#pragma unroll
        for (int j = 0; j < 4; ++j)
            bf[j] = *(const short8*)(Bs + (rb + j * 16) * 32 + sa_off);
#pragma unroll
        for (int i = 0; i < 4; ++i)
#pragma unroll
            for (int j = 0; j < 4; ++j)
                acc[i][j] = mfma16x32(af[i], bf[j], acc[i][j]);
    }

    const float sc = (mode == 0) ? QSCALE : 1.f;
#pragma unroll
    for (int i = 0; i < 4; ++i) {
#pragma unroll
        for (int j = 0; j < 4; ++j) {
            const int c = col0 + wn * 64 + j * 16 + l16;
            const float bv = bias[c];
#pragma unroll
            for (int rr = 0; rr < 4; ++rr) {
                const int r = row0 + wm * 64 + i * 16 + quad * 4 + rr;
                const float v = (acc[i][j][rr] + bv) * sc;
                const int b = r >> 11, s = r & 2047, h = c >> 6, d = c & 63;
                if (mode <= 1) {
                    ushort_t* D = (mode == 0) ? Dq : Dk;
                    D[(((b * 16 + h) * 2048 + s) << 6) + d] = f2bf(v);
                } else {
                    Dv[(((b * 16 + h) * 64 + d) << 11) + s] = f2bf(v);
                }
            }
        }
    }
}

// ---------------------------------------------------------------------------
// Output GEMM: Dout[r][c] = sum_k A[r][k]*WoT[c][k] + bias[c], f32 out.
// 64x128 tile -> 512 blocks (2 blocks/CU).
// ---------------------------------------------------------------------------
__global__ __launch_bounds__(256) void gemm64(
    const ushort_t* __restrict__ A, const ushort_t* __restrict__ Bt,
    const float* __restrict__ bias, float* __restrict__ Dout)
{
    __shared__ __align__(16) ushort_t As[64 * 32];
    __shared__ __align__(16) ushort_t Bs[128 * 32];
    const int tid = threadIdx.x;
    const int lane = tid & 63, wid = tid >> 6;
    const int quad = lane >> 4, l16 = lane & 15;
    const int wm = wid >> 1, wn = wid & 1;
    const int row0 = blockIdx.y << 6, col0 = blockIdx.x << 7;

    floatx4 acc[2][4];
#pragma unroll
    for (int i = 0; i < 2; ++i)
#pragma unroll
        for (int j = 0; j < 4; ++j) acc[i][j] = zero4();

    const int rA = tid >> 2, cA = (tid & 3) ^ (rA & 3);
    const ushort_t* gA = A + (size_t)(row0 + rA) * 1024 + cA * 8;
    ushort_t* lA = As + tid * 8;
    const int i0 = tid, i1 = 256 + tid;
    const int rB0 = i0 >> 2, cB0 = (i0 & 3) ^ (rB0 & 3);
    const int rB1 = i1 >> 2, cB1 = (i1 & 3) ^ (rB1 & 3);
    const ushort_t* gB0 = Bt + (size_t)(col0 + rB0) * 1024 + cB0 * 8;
    const ushort_t* gB1 = Bt + (size_t)(col0 + rB1) * 1024 + cB1 * 8;
    ushort_t* lB0 = Bs + i0 * 8;  ushort_t* lB1 = Bs + i1 * 8;

    const int sa_off = (quad ^ (l16 & 3)) * 8;

    for (int k0 = 0; k0 < 1024; k0 += 32) {
        __syncthreads();
        gload16(gA + k0, lA);
        gload16(gB0 + k0, lB0);
        gload16(gB1 + k0, lB1);
        __syncthreads();

        short8 af[2], bf[4];
#pragma unroll
        for (int i = 0; i < 2; ++i)
            af[i] = *(const short8*)(As + (wm * 32 + i * 16 + l16) * 32 + sa_off);
#pragma unroll
        for (int j = 0; j < 4; ++j)
            bf[j] = *(const short8*)(Bs + (wn * 64 + j * 16 + l16) * 32 + sa_off);
#pragma unroll
        for (int i = 0; i < 2; ++i)
#pragma unroll
            for (int j = 0; j < 4; ++j)
                acc[i][j] = mfma16x32(af[i], bf[j], acc[i][j]);
    }

#pragma unroll
    for (int i = 0; i < 2; ++i)
#pragma unroll
        for (int j = 0; j < 4; ++j) {
            const int c = col0 + wn * 64 + j * 16 + l16;
            const float bv = bias[c];
#pragma unroll
            for (int rr = 0; rr < 4; ++rr) {
                const int r = row0 + wm * 32 + i * 16 + quad * 4 + rr;
                Dout[(size_t)r * 1024 + c] = acc[i][j][rr] + bv;
            }
        }
}

// ---------------------------------------------------------------------------
// Attention: R4's VERIFIED q-reuse numerics + latency-hiding schedule.
// Grid 512 = 32 bh (head-major, XCD = blk%8) x 16 q-tiles of 128 rows;
// 4 waves x 32 q-rows (two 16-row MFMA subtiles u=0,1) per block.
// Changes vs R4 (scheduling only; all fragment maps bit-identical):
//  - 256-thread blocks: 4 waves share each barrier + staging burst.
//  - Double-buffered LDS (2x16KB), ONE barrier per kt-step; STAGE(next)
//    issued right after the barrier so loads complete under compute and the
//    compiler's vmcnt(0)-before-s_barrier drain is cheap (m97 pattern).
//  - Denominator on the MFMA pipe: lsum = mfma(pf, ones, lsum) sums the
//    EXACT truncated-bf16 P used in PV; lsum C/D rows align with o_acc rows
//    (same A-operand => same m-map), so epilogue needs no shuffles and the
//    32 f32 adds/lane/step leave the VALU pipe.
// ---------------------------------------------------------------------------
__global__ __launch_bounds__(256, 2) void attn64q(
    const ushort_t* __restrict__ Q, const ushort_t* __restrict__ K,
    const ushort_t* __restrict__ Vt, ushort_t* __restrict__ Out)
{
    __shared__ __align__(16) ushort_t Ks[2][64 * 64];  // [kcol][d], swizzled chunks
    __shared__ __align__(16) ushort_t Vs[2][64 * 64];  // [d][kcol], swizzled chunks

    const int tid = threadIdx.x;
    const int lane = tid & 63, wid = tid >> 6;   // 4 waves
    const int quad = lane >> 4, l16 = lane & 15;
    const int blk = blockIdx.x;
    const int bh = blk & 31;          // head-major: XCD = blk%8 = bh%8
    const int q0 = (blk >> 5) << 7;   // 128 q-rows per block

    const ushort_t* Qh = Q + (size_t)bh * (2048 * 64);
    const ushort_t* Kh = K + (size_t)bh * (2048 * 64);
    const ushort_t* Vh = Vt + (size_t)bh * (64 * 2048);

    // Q fragments for both subtiles (B-operand: n=qrow=l16, k=8*quad+j)
    short8 qf0[2], qf1[2];
#pragma unroll
    for (int u = 0; u < 2; ++u) {
        const int qr = q0 + wid * 32 + u * 16 + l16;
        qf0[u] = *(const short8*)(Qh + (size_t)qr * 64 + quad * 8);
        qf1[u] = *(const short8*)(Qh + (size_t)qr * 64 + 32 + quad * 8);
    }

    floatx4 o_acc[2][4], lsum[2];
#pragma unroll
    for (int u = 0; u < 2; ++u) {
        lsum[u] = zero4();
#pragma unroll
        for (int d = 0; d < 4; ++d) o_acc[u][d] = zero4();
    }

    // staging: 2 slots per thread per tensor (256 thr x 2 = 512 slots).
    // slot s = tid + 256*i: kr = tid>>3 + 32i, kc = (tid&7)^(kr&7) (i-invariant).
    const int kr = tid >> 3, kc = (tid & 7) ^ (kr & 7);
    const ushort_t* gK0 = Kh + (size_t)kr * 64 + kc * 8;
    const ushort_t* gV0 = Vh + (size_t)kr * 2048 + kc * 8;
    ushort_t* lK0 = &Ks[0][0] + tid * 8;
    ushort_t* lV0 = &Vs[0][0] + tid * 8;

    const int l7 = l16 & 7;
    const int q2 = quad >> 1, q1 = (quad & 1) * 4;

    union { uint_t u4[4]; short8 s; } onep;
    onep.u4[0] = onep.u4[1] = onep.u4[2] = onep.u4[3] = 0x3f803f80u;  // bf16 1.0
    const short8 ones = onep.s;

#define STAGE(pp, kto) do {                                            \
        gload16(gK0 + (size_t)(kto) * 64,         lK0 + (pp) * 4096);  \
        gload16(gK0 + (size_t)(kto) * 64 + 2048,  lK0 + (pp) * 4096 + 2048); \
        gload16(gV0 + (kto),                      lV0 + (pp) * 4096);  \
        gload16(gV0 + (kto) + 65536,              lV0 + (pp) * 4096 + 2048); \
    } while (0)

    STAGE(0, 0);
#pragma unroll 2
    for (int it = 0; it < 32; ++it) {
        const int p = it & 1;
        __syncthreads();                           // drains prev STAGE (vmcnt0)
        if (it < 31) STAGE(p ^ 1, (it + 1) * 64);  // overlaps with compute below
        const ushort_t* ksp = &Ks[p][0];
        const ushort_t* vsp = &Vs[p][0];

        // S^T tiles: A = K-frag (m=kcol) read ONCE, B = Q-frag per subtile
        floatx4 sa[2][4];
#pragma unroll
        for (int g = 0; g < 4; ++g) {
            const int row = g * 16 + l16;  // kcol
            const short8 kf0 = *(const short8*)(ksp + row * 64 + ((quad ^ l7) * 8));
            const short8 kf1 = *(const short8*)(ksp + row * 64 + (((quad + 4) ^ l7) * 8));
#pragma unroll
            for (int u = 0; u < 2; ++u) {
                floatx4 t0 = mfma16x32(kf0, qf0[u], zero4());
                sa[u][g] = mfma16x32(kf1, qf1[u], t0);
            }
        }

        // softmax + pack two g-blocks per K=32 PV MFMA; V-frags shared by subtiles
#pragma unroll
        for (int G = 0; G < 2; ++G) {
            short8 pf[2];
#pragma unroll
            for (int u = 0; u < 2; ++u) {
                uint_t ub[8];
#pragma unroll
                for (int t = 0; t < 8; ++t) {
                    const int g = G * 2 + (t >> 2), r = t & 3;
                    const float e = __builtin_amdgcn_exp2f(fminf(sa[u][g][r], 80.f));
                    ub[t] = __float_as_uint(e) & 0xffff0000u;  // truncate to bf16
                }
                union { uint_t u4[4]; short8 s; } pc;
                pc.u4[0] = (ub[0] >> 16) | ub[1];
                pc.u4[1] = (ub[2] >> 16) | ub[3];
                pc.u4[2] = (ub[4] >> 16) | ub[5];
                pc.u4[3] = (ub[6] >> 16) | ub[7];
                pf[u] = pc.s;
                // denominator via MFMA: sums the exact truncated P used in PV
                lsum[u] = mfma16x32(pf[u], ones, lsum[u]);
            }
            const int ch0 = ((4 * G + q2) ^ l7) * 8;
            const int ch1 = ((4 * G + 2 + q2) ^ l7) * 8;
#pragma unroll
            for (int db = 0; db < 4; ++db) {
                const int vbase = (db * 16 + l16) * 64 + q1;
                const uint2 v0 = *(const uint2*)(vsp + vbase + ch0);
                const uint2 v1 = *(const uint2*)(vsp + vbase + ch1);
                union { uint_t u4[4]; short8 s; } vc;
                vc.u4[0] = v0.x; vc.u4[1] = v0.y; vc.u4[2] = v1.x; vc.u4[3] = v1.y;
                o_acc[0][db] = mfma16x32(pf[0], vc.s, o_acc[0][db]);
                o_acc[1][db] = mfma16x32(pf[1], vc.s, o_acc[1][db]);
            }
        }
    }
#undef STAGE

    // epilogue: lsum[u][r] is the denom of qrow quad*4+r (same C/D row map as
    // o_acc) — no shuffles needed.
    const int b = bh >> 4, hh = bh & 15;
#pragma unroll
    for (int u = 0; u < 2; ++u) {
        const int s0 = q0 + wid * 32 + u * 16 + quad * 4;
#pragma unroll
        for (int r = 0; r < 4; ++r) {
            const float inv = 1.f / lsum[u][r];
#pragma unroll
            for (int db = 0; db < 4; ++db) {
                const float v = o_acc[u][db][r] * inv;
                Out[(size_t)(b * 2048 + s0 + r) * 1024 + hh * 64 + db * 16 + l16] = f2bf(v);
            }
        }
    }
}

// ---------------------------------------------------------------------------
// Launch (attn grid 512 = 32 bh x 16 q-tiles of 128 rows, 256 threads).
//  big (>=64MiB): WT@0 Qb@8M Kb@16M Vb@24M Qp@32M Kp@40M Vtp@48M An@56M
//  small (40MiB): WT@0 buf1@8M buf2@16M Qp@24M Kp@32M
// ---------------------------------------------------------------------------
extern "C" void kernel_launch(void* const* d_in, const int* in_sizes, int n_in,
                              void* d_out, int out_size, void* d_ws, size_t ws_size,
                              hipStream_t stream) {
    const float* queries = (const float*)d_in[0];
    const float* keys    = (const float*)d_in[1];
    const float* values  = (const float*)d_in[2];
    const float* Wq = (const float*)d_in[3];
    const float* bq = (const float*)d_in[4];
    const float* Wk = (const float*)d_in[5];
    const float* bk = (const float*)d_in[6];
    const float* Wv = (const float*)d_in[7];
    const float* bv = (const float*)d_in[8];
    const float* Wo = (const float*)d_in[9];
    const float* bo = (const float*)d_in[10];
    float* out = (float*)d_out;

    char* ws = (char*)d_ws;
    const size_t MB = 1024 * 1024;
    ushort_t* WT = (ushort_t*)(ws);
    const ushort_t* WoT = WT + 3 * 1048576;
    dim3 tb(256);

    transpose_w<<<dim3(256, 4), tb, 0, stream>>>(Wq, Wk, Wv, Wo, WT);

    if (ws_size >= 64 * MB) {
        ushort_t* Qb  = (ushort_t*)(ws + 8 * MB);
        ushort_t* Kb  = (ushort_t*)(ws + 16 * MB);
        ushort_t* Vb  = (ushort_t*)(ws + 24 * MB);
        ushort_t* Qp  = (ushort_t*)(ws + 32 * MB);
        ushort_t* Kp  = (ushort_t*)(ws + 40 * MB);
        ushort_t* Vtp = (ushort_t*)(ws + 48 * MB);
        ushort_t* An  = (ushort_t*)(ws + 56 * MB);
        cvt_bf16<<<dim3(6144), tb, 0, stream>>>(queries, keys, values, Qb, Kb, Vb);
        gemm_bt<<<dim3(8, 32, 3), tb, 0, stream>>>(Qb, Kb, Vb, WT,
            bq, bk, bv, Qp, Kp, Vtp, 0);
        attn64q<<<dim3(512), tb, 0, stream>>>(Qp, Kp, Vtp, An);
        gemm64<<<dim3(8, 64), tb, 0, stream>>>(An, WoT, bo, out);
    } else {
        ushort_t* buf1 = (ushort_t*)(ws + 8 * MB);
        ushort_t* buf2 = (ushort_t*)(ws + 16 * MB);
        ushort_t* Qp   = (ushort_t*)(ws + 24 * MB);
        ushort_t* Kp   = (ushort_t*)(ws + 32 * MB);
        cvt_bf16<<<dim3(4096), tb, 0, stream>>>(queries, keys, keys, buf1, buf2, buf2);
        gemm_bt<<<dim3(8, 32, 2), tb, 0, stream>>>(buf1, buf2, buf2, WT,
            bq, bk, bk, Qp, Kp, Kp, 0);
        cvt_bf16<<<dim3(2048), tb, 0, stream>>>(values, values, values, buf1, buf1, buf1);
        gemm_bt<<<dim3(8, 32, 1), tb, 0, stream>>>(buf1, buf1, buf1, WT,
            bv, bv, bv, buf2, buf2, buf2, 2);   // mode 2: V -> Vtp = buf2
        attn64q<<<dim3(512), tb, 0, stream>>>(Qp, Kp, buf2, buf1);
        gemm64<<<dim3(8, 64), tb, 0, stream>>>(buf1, WoT, bo, out);
    }
}

// Round 7
// 229.630 us; speedup vs baseline: 1.0510x; 1.0042x over previous
//
#include <hip/hip_runtime.h>

typedef unsigned short ushort_t;
typedef unsigned int uint_t;
typedef __attribute__((ext_vector_type(8))) short short8;
typedef __attribute__((ext_vector_type(4))) float floatx4;

#define QSCALE 0.03187936f  // (1/sqrt(2048)) * log2(e): quirk scale + exp2 fold

__device__ __forceinline__ ushort_t f2bf(float f) {
    union { float f; uint_t u; } c; c.f = f;
    uint_t u = c.u;
    return (ushort_t)((u + 0x7fffu + ((u >> 16) & 1u)) >> 16);  // RNE
}
__device__ __forceinline__ floatx4 mfma16x32(short8 a, short8 b, floatx4 c) {
    return __builtin_amdgcn_mfma_f32_16x16x32_bf16(a, b, c, 0, 0, 0);
}
__device__ __forceinline__ floatx4 zero4() { floatx4 z = {0.f, 0.f, 0.f, 0.f}; return z; }

// Async 16B global->LDS. Per-lane lds ptr = base + lane*16B slot (HW uses
// lane0's ptr as wave base and strides lane*16 — matches our linear slots).
__device__ __forceinline__ void gload16(const ushort_t* g, ushort_t* l) {
    __builtin_amdgcn_global_load_lds(
        (const __attribute__((address_space(1))) void*)g,
        (__attribute__((address_space(3))) void*)l, 16, 0, 0);
}

// ---------------------------------------------------------------------------
// f32 -> bf16 convert (RNE), 8 elems/thread, up to 3 tensors of 4M elems.
// ---------------------------------------------------------------------------
__global__ __launch_bounds__(256) void cvt_bf16(
    const float* __restrict__ s0, const float* __restrict__ s1,
    const float* __restrict__ s2, ushort_t* __restrict__ d0,
    ushort_t* __restrict__ d1, ushort_t* __restrict__ d2)
{
    const int which = blockIdx.x >> 11;
    const int blk = blockIdx.x & 2047;
    const float* src = (which == 0) ? s0 : (which == 1) ? s1 : s2;
    ushort_t* dst = (which == 0) ? d0 : (which == 1) ? d1 : d2;
    const int i = (blk * 256 + threadIdx.x) * 8;
    float4 f0 = *(const float4*)(src + i);
    float4 f1 = *(const float4*)(src + i + 4);
    __align__(16) ushort_t t[8];
    t[0] = f2bf(f0.x); t[1] = f2bf(f0.y); t[2] = f2bf(f0.z); t[3] = f2bf(f0.w);
    t[4] = f2bf(f1.x); t[5] = f2bf(f1.y); t[6] = f2bf(f1.z); t[7] = f2bf(f1.w);
    *(uint4*)(dst + i) = *(uint4*)t;
}

// ---------------------------------------------------------------------------
// Fused convert+transpose: W[k][j] (1024x1024 f32) -> WT[j][k] bf16.
// ---------------------------------------------------------------------------
__global__ __launch_bounds__(256) void transpose_w(
    const float* __restrict__ W0, const float* __restrict__ W1,
    const float* __restrict__ W2, const float* __restrict__ W3,
    ushort_t* __restrict__ WT)
{
    __shared__ ushort_t tile[64][65];
    const float* W = (blockIdx.y == 0) ? W0 : (blockIdx.y == 1) ? W1
                   : (blockIdx.y == 2) ? W2 : W3;
    ushort_t* dst = WT + (size_t)blockIdx.y * (1024 * 1024);
    const int t = threadIdx.x;
    const int r = t >> 2, p = t & 3;
    const int j0 = (blockIdx.x & 15) << 6, k0 = (blockIdx.x >> 4) << 6;

    const float* src = W + (size_t)(k0 + r) * 1024 + j0 + p * 16;
    float4 f0 = *(const float4*)(src);
    float4 f1 = *(const float4*)(src + 4);
    float4 f2 = *(const float4*)(src + 8);
    float4 f3 = *(const float4*)(src + 12);
    ushort_t* tr = &tile[r][p * 16];
    tr[0] = f2bf(f0.x); tr[1] = f2bf(f0.y); tr[2]  = f2bf(f0.z); tr[3]  = f2bf(f0.w);
    tr[4] = f2bf(f1.x); tr[5] = f2bf(f1.y); tr[6]  = f2bf(f1.z); tr[7]  = f2bf(f1.w);
    tr[8] = f2bf(f2.x); tr[9] = f2bf(f2.y); tr[10] = f2bf(f2.z); tr[11] = f2bf(f2.w);
    tr[12] = f2bf(f3.x); tr[13] = f2bf(f3.y); tr[14] = f2bf(f3.z); tr[15] = f2bf(f3.w);
    __syncthreads();
    __align__(16) ushort_t buf[16];
#pragma unroll
    for (int i = 0; i < 16; ++i) buf[i] = tile[p * 16 + i][r];
    ushort_t* o = dst + (size_t)(j0 + r) * 1024 + k0 + p * 16;
    *(uint4*)(o)     = *(uint4*)(buf);
    *(uint4*)(o + 8) = *(uint4*)(buf + 8);
}

// ---------------------------------------------------------------------------
// Projection GEMM: C[r][c] = sum_k A[r][k]*WT[c][k] + bias[c]. 4096x1024x1024.
// 128x128 tile, BK=32, global_load_lds staging, XOR-swizzled LDS chunks.
// mode = blockIdx.z + zbase: 0: Q -> [B,H,S,64] *QSCALE; 1: K -> [B,H,S,64];
// 2: V -> [B,H,64,S].
// ---------------------------------------------------------------------------
__global__ __launch_bounds__(256) void gemm_bt(
    const ushort_t* __restrict__ A0, const ushort_t* __restrict__ A1,
    const ushort_t* __restrict__ A2, const ushort_t* __restrict__ WT,
    const float* __restrict__ b0, const float* __restrict__ b1,
    const float* __restrict__ b2,
    ushort_t* __restrict__ Dq, ushort_t* __restrict__ Dk,
    ushort_t* __restrict__ Dv, int zbase)
{
    __shared__ __align__(16) ushort_t As[128 * 32];
    __shared__ __align__(16) ushort_t Bs[128 * 32];

    const int mode = blockIdx.z + zbase;
    const ushort_t* A = (mode == 0) ? A0 : (mode == 1) ? A1 : A2;
    const float* bias = (mode == 0) ? b0 : (mode == 1) ? b1 : b2;
    const ushort_t* Bt = WT + (size_t)mode * 1048576;

    const int tid = threadIdx.x;
    const int lane = tid & 63, wid = tid >> 6;
    const int quad = lane >> 4, l16 = lane & 15;
    const int wm = wid >> 1, wn = wid & 1;
    const int row0 = blockIdx.y << 7, col0 = blockIdx.x << 7;

    floatx4 acc[4][4];
#pragma unroll
    for (int i = 0; i < 4; ++i)
#pragma unroll
        for (int j = 0; j < 4; ++j) acc[i][j] = zero4();

    const int i0 = tid, i1 = 256 + tid;
    const int r0_ = i0 >> 2, c0_ = (i0 & 3) ^ (r0_ & 3);
    const int r1_ = i1 >> 2, c1_ = (i1 & 3) ^ (r1_ & 3);
    const ushort_t* gA0 = A  + (size_t)(row0 + r0_) * 1024 + c0_ * 8;
    const ushort_t* gA1 = A  + (size_t)(row0 + r1_) * 1024 + c1_ * 8;
    const ushort_t* gB0 = Bt + (size_t)(col0 + r0_) * 1024 + c0_ * 8;
    const ushort_t* gB1 = Bt + (size_t)(col0 + r1_) * 1024 + c1_ * 8;
    ushort_t* lA0 = As + i0 * 8;  ushort_t* lA1 = As + i1 * 8;
    ushort_t* lB0 = Bs + i0 * 8;  ushort_t* lB1 = Bs + i1 * 8;

    const int ra = wm * 64 + l16, rb = wn * 64 + l16;
    const int sa_off = (quad ^ (l16 & 3)) * 8;

    for (int k0 = 0; k0 < 1024; k0 += 32) {
        __syncthreads();
        gload16(gA0 + k0, lA0);
        gload16(gA1 + k0, lA1);
        gload16(gB0 + k0, lB0);
        gload16(gB1 + k0, lB1);
        __syncthreads();

        short8 af[4], bf[4];
#pragma unroll
        for (int i = 0; i < 4; ++i)
            af[i] = *(const short8*)(As + (ra + i * 16) * 32 + sa_off);
#pragma unroll
        for (int j = 0; j < 4; ++j)
            bf[j] = *(const short8*)(Bs + (rb + j * 16) * 32 + sa_off);
#pragma unroll
        for (int i = 0; i < 4; ++i)
#pragma unroll
            for (int j = 0; j < 4; ++j)
                acc[i][j] = mfma16x32(af[i], bf[j], acc[i][j]);
    }

    const float sc = (mode == 0) ? QSCALE : 1.f;
#pragma unroll
    for (int i = 0; i < 4; ++i) {
#pragma unroll
        for (int j = 0; j < 4; ++j) {
            const int c = col0 + wn * 64 + j * 16 + l16;
            const float bv = bias[c];
#pragma unroll
            for (int rr = 0; rr < 4; ++rr) {
                const int r = row0 + wm * 64 + i * 16 + quad * 4 + rr;
                const float v = (acc[i][j][rr] + bv) * sc;
                const int b = r >> 11, s = r & 2047, h = c >> 6, d = c & 63;
                if (mode <= 1) {
                    ushort_t* D = (mode == 0) ? Dq : Dk;
                    D[(((b * 16 + h) * 2048 + s) << 6) + d] = f2bf(v);
                } else {
                    Dv[(((b * 16 + h) * 64 + d) << 11) + s] = f2bf(v);
                }
            }
        }
    }
}

// ---------------------------------------------------------------------------
// Output GEMM: Dout[r][c] = sum_k A[r][k]*WoT[c][k] + bias[c], f32 out.
// 64x128 tile -> 512 blocks (2 blocks/CU).
// ---------------------------------------------------------------------------
__global__ __launch_bounds__(256) void gemm64(
    const ushort_t* __restrict__ A, const ushort_t* __restrict__ Bt,
    const float* __restrict__ bias, float* __restrict__ Dout)
{
    __shared__ __align__(16) ushort_t As[64 * 32];
    __shared__ __align__(16) ushort_t Bs[128 * 32];
    const int tid = threadIdx.x;
    const int lane = tid & 63, wid = tid >> 6;
    const int quad = lane >> 4, l16 = lane & 15;
    const int wm = wid >> 1, wn = wid & 1;
    const int row0 = blockIdx.y << 6, col0 = blockIdx.x << 7;

    floatx4 acc[2][4];
#pragma unroll
    for (int i = 0; i < 2; ++i)
#pragma unroll
        for (int j = 0; j < 4; ++j) acc[i][j] = zero4();

    const int rA = tid >> 2, cA = (tid & 3) ^ (rA & 3);
    const ushort_t* gA = A + (size_t)(row0 + rA) * 1024 + cA * 8;
    ushort_t* lA = As + tid * 8;
    const int i0 = tid, i1 = 256 + tid;
    const int rB0 = i0 >> 2, cB0 = (i0 & 3) ^ (rB0 & 3);
    const int rB1 = i1 >> 2, cB1 = (i1 & 3) ^ (rB1 & 3);
    const ushort_t* gB0 = Bt + (size_t)(col0 + rB0) * 1024 + cB0 * 8;
    const ushort_t* gB1 = Bt + (size_t)(col0 + rB1) * 1024 + cB1 * 8;
    ushort_t* lB0 = Bs + i0 * 8;  ushort_t* lB1 = Bs + i1 * 8;

    const int sa_off = (quad ^ (l16 & 3)) * 8;

    for (int k0 = 0; k0 < 1024; k0 += 32) {
        __syncthreads();
        gload16(gA + k0, lA);
        gload16(gB0 + k0, lB0);
        gload16(gB1 + k0, lB1);
        __syncthreads();

        short8 af[2], bf[4];
#pragma unroll
        for (int i = 0; i < 2; ++i)
            af[i] = *(const short8*)(As + (wm * 32 + i * 16 + l16) * 32 + sa_off);
#pragma unroll
        for (int j = 0; j < 4; ++j)
            bf[j] = *(const short8*)(Bs + (wn * 64 + j * 16 + l16) * 32 + sa_off);
#pragma unroll
        for (int i = 0; i < 2; ++i)
#pragma unroll
            for (int j = 0; j < 4; ++j)
                acc[i][j] = mfma16x32(af[i], bf[j], acc[i][j]);
    }

#pragma unroll
    for (int i = 0; i < 2; ++i)
#pragma unroll
        for (int j = 0; j < 4; ++j) {
            const int c = col0 + wn * 64 + j * 16 + l16;
            const float bv = bias[c];
#pragma unroll
            for (int rr = 0; rr < 4; ++rr) {
                const int r = row0 + wm * 32 + i * 16 + quad * 4 + rr;
                Dout[(size_t)r * 1024 + c] = acc[i][j][rr] + bv;
            }
        }
}

// ---------------------------------------------------------------------------
// Attention: R5's VERIFIED numerics, KVBLK=128 (two bit-identical 64-kcol
// halves) + v_perm pack.
// Grid 512 = 32 bh (head-major, XCD = blk%8) x 16 q-tiles of 128 rows;
// 4 waves x 32 q-rows (two 16-row MFMA subtiles u=0,1) per block.
// Changes vs R5 (scheduling + VALU only; all fragment maps bit-identical):
//  - KVBLK=128 as halves: Ks[2][2][64*64]/Vs[2][2][64*64] (64KB, 2 blk/CU).
//    Barriers 32 -> 16; each compute phase has 2x independent work to
//    overlap the vmcnt(0)+barrier drain (R5 diagnosis: ~50% stall/step).
//  - Pack via v_perm_b32 (one op per bf16 pair, replaces and+lshr+or; same
//    TRUNCATED bits as R5's verified pack). lsum still sums the exact PV
//    operand via MFMA(pf, ones).
// ---------------------------------------------------------------------------
__global__ __launch_bounds__(256, 2) void attn64q(
    const ushort_t* __restrict__ Q, const ushort_t* __restrict__ K,
    const ushort_t* __restrict__ Vt, ushort_t* __restrict__ Out)
{
    __shared__ __align__(16) ushort_t Ks[2][2][64 * 64];  // [buf][half][kcol][d]
    __shared__ __align__(16) ushort_t Vs[2][2][64 * 64];  // [buf][half][d][kcol]

    const int tid = threadIdx.x;
    const int lane = tid & 63, wid = tid >> 6;   // 4 waves
    const int quad = lane >> 4, l16 = lane & 15;
    const int blk = blockIdx.x;
    const int bh = blk & 31;          // head-major: XCD = blk%8 = bh%8
    const int q0 = (blk >> 5) << 7;   // 128 q-rows per block

    const ushort_t* Qh = Q + (size_t)bh * (2048 * 64);
    const ushort_t* Kh = K + (size_t)bh * (2048 * 64);
    const ushort_t* Vh = Vt + (size_t)bh * (64 * 2048);

    // Q fragments for both subtiles (B-operand: n=qrow=l16, k=8*quad+j)
    short8 qf0[2], qf1[2];
#pragma unroll
    for (int u = 0; u < 2; ++u) {
        const int qr = q0 + wid * 32 + u * 16 + l16;
        qf0[u] = *(const short8*)(Qh + (size_t)qr * 64 + quad * 8);
        qf1[u] = *(const short8*)(Qh + (size_t)qr * 64 + 32 + quad * 8);
    }

    floatx4 o_acc[2][4], lsum[2];
#pragma unroll
    for (int u = 0; u < 2; ++u) {
        lsum[u] = zero4();
#pragma unroll
        for (int d = 0; d < 4; ++d) o_acc[u][d] = zero4();
    }

    // staging slots (identical to R5 per half): slot s = tid + 256*i,
    // kr = tid>>3 (+32i), kc = (tid&7)^(kr&7) (i-invariant).
    const int kr = tid >> 3, kc = (tid & 7) ^ (kr & 7);
    const ushort_t* gK0 = Kh + (size_t)kr * 64 + kc * 8;
    const ushort_t* gV0 = Vh + (size_t)kr * 2048 + kc * 8;

    const int l7 = l16 & 7;
    const int q2 = quad >> 1, q1 = (quad & 1) * 4;

    union { uint_t u4[4]; short8 s; } onep;
    onep.u4[0] = onep.u4[1] = onep.u4[2] = onep.u4[3] = 0x3f803f80u;  // bf16 1.0
    const short8 ones = onep.s;

    // STAGE: both 64-kcol halves of buffer pp for K-tile starting at kto.
    // Per half: K rows kto+64h .. +63 (global +h*4096 elems), V cols +64h.
#define STAGE(pp, kto) do {                                                  \
        _Pragma("unroll")                                                    \
        for (int hf_ = 0; hf_ < 2; ++hf_) {                                  \
            gload16(gK0 + (size_t)(kto) * 64 + hf_ * 4096,                   \
                    &Ks[pp][hf_][tid * 8]);                                  \
            gload16(gK0 + (size_t)(kto) * 64 + hf_ * 4096 + 2048,            \
                    &Ks[pp][hf_][tid * 8 + 2048]);                           \
            gload16(gV0 + (kto) + hf_ * 64,                                  \
                    &Vs[pp][hf_][tid * 8]);                                  \
            gload16(gV0 + (kto) + hf_ * 64 + 65536,                          \
                    &Vs[pp][hf_][tid * 8 + 2048]);                           \
        }                                                                    \
    } while (0)

    STAGE(0, 0);
    for (int it = 0; it < 16; ++it) {
        const int p = it & 1;
        __syncthreads();                            // drains prev STAGE (vmcnt0)
        if (it < 15) STAGE(p ^ 1, (it + 1) * 128);  // overlaps with compute below

#pragma unroll
        for (int hf = 0; hf < 2; ++hf) {
            const ushort_t* ksp = &Ks[p][hf][0];
            const ushort_t* vsp = &Vs[p][hf][0];

            // S^T tiles: A = K-frag (m=kcol) read ONCE, B = Q-frag per subtile
            floatx4 sa[2][4];
#pragma unroll
            for (int g = 0; g < 4; ++g) {
                const int row = g * 16 + l16;  // kcol
                const short8 kf0 = *(const short8*)(ksp + row * 64 + ((quad ^ l7) * 8));
                const short8 kf1 = *(const short8*)(ksp + row * 64 + (((quad + 4) ^ l7) * 8));
#pragma unroll
                for (int u = 0; u < 2; ++u) {
                    floatx4 t0 = mfma16x32(kf0, qf0[u], zero4());
                    sa[u][g] = mfma16x32(kf1, qf1[u], t0);
                }
            }

            // softmax + pack two g-blocks per K=32 PV MFMA; V-frags shared
#pragma unroll
            for (int G = 0; G < 2; ++G) {
                short8 pf[2];
#pragma unroll
                for (int u = 0; u < 2; ++u) {
                    uint_t ub[8];
#pragma unroll
                    for (int t = 0; t < 8; ++t) {
                        const int g = G * 2 + (t >> 2), r = t & 3;
                        const float e = __builtin_amdgcn_exp2f(fminf(sa[u][g][r], 80.f));
                        ub[t] = __float_as_uint(e);
                    }
                    union { uint_t u4[4]; short8 s; } pc;
                    // one v_perm per pair: dst = {hi16(ub[2w+1]), hi16(ub[2w])}
                    // (identical truncated bits to the verified shift/or pack)
                    pc.u4[0] = __builtin_amdgcn_perm(ub[1], ub[0], 0x07060302u);
                    pc.u4[1] = __builtin_amdgcn_perm(ub[3], ub[2], 0x07060302u);
                    pc.u4[2] = __builtin_amdgcn_perm(ub[5], ub[4], 0x07060302u);
                    pc.u4[3] = __builtin_amdgcn_perm(ub[7], ub[6], 0x07060302u);
                    pf[u] = pc.s;
                    // denominator via MFMA: sums the exact truncated P used in PV
                    lsum[u] = mfma16x32(pf[u], ones, lsum[u]);
                }
                const int ch0 = ((4 * G + q2) ^ l7) * 8;
                const int ch1 = ((4 * G + 2 + q2) ^ l7) * 8;
#pragma unroll
                for (int db = 0; db < 4; ++db) {
                    const int vbase = (db * 16 + l16) * 64 + q1;
                    const uint2 v0 = *(const uint2*)(vsp + vbase + ch0);
                    const uint2 v1 = *(const uint2*)(vsp + vbase + ch1);
                    union { uint_t u4[4]; short8 s; } vc;
                    vc.u4[0] = v0.x; vc.u4[1] = v0.y; vc.u4[2] = v1.x; vc.u4[3] = v1.y;
                    o_acc[0][db] = mfma16x32(pf[0], vc.s, o_acc[0][db]);
                    o_acc[1][db] = mfma16x32(pf[1], vc.s, o_acc[1][db]);
                }
            }
        }
    }
#undef STAGE

    // epilogue: lsum[u][r] is the denom of qrow quad*4+r (same C/D row map as
    // o_acc) — no shuffles needed.
    const int b = bh >> 4, hh = bh & 15;
#pragma unroll
    for (int u = 0; u < 2; ++u) {
        const int s0 = q0 + wid * 32 + u * 16 + quad * 4;
#pragma unroll
        for (int r = 0; r < 4; ++r) {
            const float inv = 1.f / lsum[u][r];
#pragma unroll
            for (int db = 0; db < 4; ++db) {
                const float v = o_acc[u][db][r] * inv;
                Out[(size_t)(b * 2048 + s0 + r) * 1024 + hh * 64 + db * 16 + l16] = f2bf(v);
            }
        }
    }
}

// ---------------------------------------------------------------------------
// Launch (attn grid 512 = 32 bh x 16 q-tiles of 128 rows, 256 threads).
//  big (>=64MiB): WT@0 Qb@8M Kb@16M Vb@24M Qp@32M Kp@40M Vtp@48M An@56M
//  small (40MiB): WT@0 buf1@8M buf2@16M Qp@24M Kp@32M
// ---------------------------------------------------------------------------
extern "C" void kernel_launch(void* const* d_in, const int* in_sizes, int n_in,
                              void* d_out, int out_size, void* d_ws, size_t ws_size,
                              hipStream_t stream) {
    const float* queries = (const float*)d_in[0];
    const float* keys    = (const float*)d_in[1];
    const float* values  = (const float*)d_in[2];
    const float* Wq = (const float*)d_in[3];
    const float* bq = (const float*)d_in[4];
    const float* Wk = (const float*)d_in[5];
    const float* bk = (const float*)d_in[6];
    const float* Wv = (const float*)d_in[7];
    const float* bv = (const float*)d_in[8];
    const float* Wo = (const float*)d_in[9];
    const float* bo = (const float*)d_in[10];
    float* out = (float*)d_out;

    char* ws = (char*)d_ws;
    const size_t MB = 1024 * 1024;
    ushort_t* WT = (ushort_t*)(ws);
    const ushort_t* WoT = WT + 3 * 1048576;
    dim3 tb(256);

    transpose_w<<<dim3(256, 4), tb, 0, stream>>>(Wq, Wk, Wv, Wo, WT);

    if (ws_size >= 64 * MB) {
        ushort_t* Qb  = (ushort_t*)(ws + 8 * MB);
        ushort_t* Kb  = (ushort_t*)(ws + 16 * MB);
        ushort_t* Vb  = (ushort_t*)(ws + 24 * MB);
        ushort_t* Qp  = (ushort_t*)(ws + 32 * MB);
        ushort_t* Kp  = (ushort_t*)(ws + 40 * MB);
        ushort_t* Vtp = (ushort_t*)(ws + 48 * MB);
        ushort_t* An  = (ushort_t*)(ws + 56 * MB);
        cvt_bf16<<<dim3(6144), tb, 0, stream>>>(queries, keys, values, Qb, Kb, Vb);
        gemm_bt<<<dim3(8, 32, 3), tb, 0, stream>>>(Qb, Kb, Vb, WT,
            bq, bk, bv, Qp, Kp, Vtp, 0);
        attn64q<<<dim3(512), tb, 0, stream>>>(Qp, Kp, Vtp, An);
        gemm64<<<dim3(8, 64), tb, 0, stream>>>(An, WoT, bo, out);
    } else {
        ushort_t* buf1 = (ushort_t*)(ws + 8 * MB);
        ushort_t* buf2 = (ushort_t*)(ws + 16 * MB);
        ushort_t* Qp   = (ushort_t*)(ws + 24 * MB);
        ushort_t* Kp   = (ushort_t*)(ws + 32 * MB);
        cvt_bf16<<<dim3(4096), tb, 0, stream>>>(queries, keys, keys, buf1, buf2, buf2);
        gemm_bt<<<dim3(8, 32, 2), tb, 0, stream>>>(buf1, buf2, buf2, WT,
            bq, bk, bk, Qp, Kp, Kp, 0);
        cvt_bf16<<<dim3(2048), tb, 0, stream>>>(values, values, values, buf1, buf1, buf1);
        gemm_bt<<<dim3(8, 32, 1), tb, 0, stream>>>(buf1, buf1, buf1, WT,
            bv, bv, bv, buf2, buf2, buf2, 2);   // mode 2: V -> Vtp = buf2
        attn64q<<<dim3(512), tb, 0, stream>>>(Qp, Kp, buf2, buf1);
        gemm64<<<dim3(8, 64), tb, 0, stream>>>(buf1, WoT, bo, out);
    }
}

// Round 8
// 228.858 us; speedup vs baseline: 1.0545x; 1.0034x over previous
//
#include <hip/hip_runtime.h>

typedef unsigned short ushort_t;
typedef unsigned int uint_t;
typedef __attribute__((ext_vector_type(8))) short short8;
typedef __attribute__((ext_vector_type(4))) float floatx4;

#define QSCALE 0.03187936f  // (1/sqrt(2048)) * log2(e): quirk scale + exp2 fold

__device__ __forceinline__ ushort_t f2bf(float f) {
    union { float f; uint_t u; } c; c.f = f;
    uint_t u = c.u;
    return (ushort_t)((u + 0x7fffu + ((u >> 16) & 1u)) >> 16);  // RNE
}
__device__ __forceinline__ floatx4 mfma16x32(short8 a, short8 b, floatx4 c) {
    return __builtin_amdgcn_mfma_f32_16x16x32_bf16(a, b, c, 0, 0, 0);
}
__device__ __forceinline__ floatx4 zero4() { floatx4 z = {0.f, 0.f, 0.f, 0.f}; return z; }

// Async 16B global->LDS. Per-lane lds ptr = base + lane*16B slot (HW uses
// lane0's ptr as wave base and strides lane*16 — matches our linear slots).
__device__ __forceinline__ void gload16(const ushort_t* g, ushort_t* l) {
    __builtin_amdgcn_global_load_lds(
        (const __attribute__((address_space(1))) void*)g,
        (__attribute__((address_space(3))) void*)l, 16, 0, 0);
}

// ---------------------------------------------------------------------------
// f32 -> bf16 convert (RNE), 8 elems/thread, up to 3 tensors of 4M elems.
// ---------------------------------------------------------------------------
__global__ __launch_bounds__(256) void cvt_bf16(
    const float* __restrict__ s0, const float* __restrict__ s1,
    const float* __restrict__ s2, ushort_t* __restrict__ d0,
    ushort_t* __restrict__ d1, ushort_t* __restrict__ d2)
{
    const int which = blockIdx.x >> 11;
    const int blk = blockIdx.x & 2047;
    const float* src = (which == 0) ? s0 : (which == 1) ? s1 : s2;
    ushort_t* dst = (which == 0) ? d0 : (which == 1) ? d1 : d2;
    const int i = (blk * 256 + threadIdx.x) * 8;
    float4 f0 = *(const float4*)(src + i);
    float4 f1 = *(const float4*)(src + i + 4);
    __align__(16) ushort_t t[8];
    t[0] = f2bf(f0.x); t[1] = f2bf(f0.y); t[2] = f2bf(f0.z); t[3] = f2bf(f0.w);
    t[4] = f2bf(f1.x); t[5] = f2bf(f1.y); t[6] = f2bf(f1.z); t[7] = f2bf(f1.w);
    *(uint4*)(dst + i) = *(uint4*)t;
}

// ---------------------------------------------------------------------------
// Fused convert+transpose: W[k][j] (1024x1024 f32) -> WT[j][k] bf16.
// ---------------------------------------------------------------------------
__global__ __launch_bounds__(256) void transpose_w(
    const float* __restrict__ W0, const float* __restrict__ W1,
    const float* __restrict__ W2, const float* __restrict__ W3,
    ushort_t* __restrict__ WT)
{
    __shared__ ushort_t tile[64][65];
    const float* W = (blockIdx.y == 0) ? W0 : (blockIdx.y == 1) ? W1
                   : (blockIdx.y == 2) ? W2 : W3;
    ushort_t* dst = WT + (size_t)blockIdx.y * (1024 * 1024);
    const int t = threadIdx.x;
    const int r = t >> 2, p = t & 3;
    const int j0 = (blockIdx.x & 15) << 6, k0 = (blockIdx.x >> 4) << 6;

    const float* src = W + (size_t)(k0 + r) * 1024 + j0 + p * 16;
    float4 f0 = *(const float4*)(src);
    float4 f1 = *(const float4*)(src + 4);
    float4 f2 = *(const float4*)(src + 8);
    float4 f3 = *(const float4*)(src + 12);
    ushort_t* tr = &tile[r][p * 16];
    tr[0] = f2bf(f0.x); tr[1] = f2bf(f0.y); tr[2]  = f2bf(f0.z); tr[3]  = f2bf(f0.w);
    tr[4] = f2bf(f1.x); tr[5] = f2bf(f1.y); tr[6]  = f2bf(f1.z); tr[7]  = f2bf(f1.w);
    tr[8] = f2bf(f2.x); tr[9] = f2bf(f2.y); tr[10] = f2bf(f2.z); tr[11] = f2bf(f2.w);
    tr[12] = f2bf(f3.x); tr[13] = f2bf(f3.y); tr[14] = f2bf(f3.z); tr[15] = f2bf(f3.w);
    __syncthreads();
    __align__(16) ushort_t buf[16];
#pragma unroll
    for (int i = 0; i < 16; ++i) buf[i] = tile[p * 16 + i][r];
    ushort_t* o = dst + (size_t)(j0 + r) * 1024 + k0 + p * 16;
    *(uint4*)(o)     = *(uint4*)(buf);
    *(uint4*)(o + 8) = *(uint4*)(buf + 8);
}

// ---------------------------------------------------------------------------
// Projection GEMM: C[r][c] = sum_k A[r][k]*WT[c][k] + bias[c]. 4096x1024x1024.
// 128x128 tile, BK=32, global_load_lds staging, XOR-swizzled LDS chunks.
// mode = blockIdx.z + zbase: 0: Q -> [B,H,S,64] *QSCALE; 1: K -> [B,H,S,64];
// 2: V -> [B,H,64,S].
// ---------------------------------------------------------------------------
__global__ __launch_bounds__(256) void gemm_bt(
    const ushort_t* __restrict__ A0, const ushort_t* __restrict__ A1,
    const ushort_t* __restrict__ A2, const ushort_t* __restrict__ WT,
    const float* __restrict__ b0, const float* __restrict__ b1,
    const float* __restrict__ b2,
    ushort_t* __restrict__ Dq, ushort_t* __restrict__ Dk,
    ushort_t* __restrict__ Dv, int zbase)
{
    __shared__ __align__(16) ushort_t As[128 * 32];
    __shared__ __align__(16) ushort_t Bs[128 * 32];

    const int mode = blockIdx.z + zbase;
    const ushort_t* A = (mode == 0) ? A0 : (mode == 1) ? A1 : A2;
    const float* bias = (mode == 0) ? b0 : (mode == 1) ? b1 : b2;
    const ushort_t* Bt = WT + (size_t)mode * 1048576;

    const int tid = threadIdx.x;
    const int lane = tid & 63, wid = tid >> 6;
    const int quad = lane >> 4, l16 = lane & 15;
    const int wm = wid >> 1, wn = wid & 1;
    const int row0 = blockIdx.y << 7, col0 = blockIdx.x << 7;

    floatx4 acc[4][4];
#pragma unroll
    for (int i = 0; i < 4; ++i)
#pragma unroll
        for (int j = 0; j < 4; ++j) acc[i][j] = zero4();

    const int i0 = tid, i1 = 256 + tid;
    const int r0_ = i0 >> 2, c0_ = (i0 & 3) ^ (r0_ & 3);
    const int r1_ = i1 >> 2, c1_ = (i1 & 3) ^ (r1_ & 3);
    const ushort_t* gA0 = A  + (size_t)(row0 + r0_) * 1024 + c0_ * 8;
    const ushort_t* gA1 = A  + (size_t)(row0 + r1_) * 1024 + c1_ * 8;
    const ushort_t* gB0 = Bt + (size_t)(col0 + r0_) * 1024 + c0_ * 8;
    const ushort_t* gB1 = Bt + (size_t)(col0 + r1_) * 1024 + c1_ * 8;
    ushort_t* lA0 = As + i0 * 8;  ushort_t* lA1 = As + i1 * 8;
    ushort_t* lB0 = Bs + i0 * 8;  ushort_t* lB1 = Bs + i1 * 8;

    const int ra = wm * 64 + l16, rb = wn * 64 + l16;
    const int sa_off = (quad ^ (l16 & 3)) * 8;

    for (int k0 = 0; k0 < 1024; k0 += 32) {
        __syncthreads();
        gload16(gA0 + k0, lA0);
        gload16(gA1 + k0, lA1);
        gload16(gB0 + k0, lB0);
        gload16(gB1 + k0, lB1);
        __syncthreads();

        short8 af[4], bf[4];
#pragma unroll
        for (int i = 0; i < 4; ++i)
            af[i] = *(const short8*)(As + (ra + i * 16) * 32 + sa_off);
#pragma unroll
        for (int j = 0; j < 4; ++j)
            bf[j] = *(const short8*)(Bs + (rb + j * 16) * 32 + sa_off);
#pragma unroll
        for (int i = 0; i < 4; ++i)
#pragma unroll
            for (int j = 0; j < 4; ++j)
                acc[i][j] = mfma16x32(af[i], bf[j], acc[i][j]);
    }

    const float sc = (mode == 0) ? QSCALE : 1.f;
#pragma unroll
    for (int i = 0; i < 4; ++i) {
#pragma unroll
        for (int j = 0; j < 4; ++j) {
            const int c = col0 + wn * 64 + j * 16 + l16;
            const float bv = bias[c];
#pragma unroll
            for (int rr = 0; rr < 4; ++rr) {
                const int r = row0 + wm * 64 + i * 16 + quad * 4 + rr;
                const float v = (acc[i][j][rr] + bv) * sc;
                const int b = r >> 11, s = r & 2047, h = c >> 6, d = c & 63;
                if (mode <= 1) {
                    ushort_t* D = (mode == 0) ? Dq : Dk;
                    D[(((b * 16 + h) * 2048 + s) << 6) + d] = f2bf(v);
                } else {
                    Dv[(((b * 16 + h) * 64 + d) << 11) + s] = f2bf(v);
                }
            }
        }
    }
}

// ---------------------------------------------------------------------------
// Output GEMM: Dout[r][c] = sum_k A[r][k]*WoT[c][k] + bias[c], f32 out.
// 64x128 tile -> 512 blocks (2 blocks/CU).
// ---------------------------------------------------------------------------
__global__ __launch_bounds__(256) void gemm64(
    const ushort_t* __restrict__ A, const ushort_t* __restrict__ Bt,
    const float* __restrict__ bias, float* __restrict__ Dout)
{
    __shared__ __align__(16) ushort_t As[64 * 32];
    __shared__ __align__(16) ushort_t Bs[128 * 32];
    const int tid = threadIdx.x;
    const int lane = tid & 63, wid = tid >> 6;
    const int quad = lane >> 4, l16 = lane & 15;
    const int wm = wid >> 1, wn = wid & 1;
    const int row0 = blockIdx.y << 6, col0 = blockIdx.x << 7;

    floatx4 acc[2][4];
#pragma unroll
    for (int i = 0; i < 2; ++i)
#pragma unroll
        for (int j = 0; j < 4; ++j) acc[i][j] = zero4();

    const int rA = tid >> 2, cA = (tid & 3) ^ (rA & 3);
    const ushort_t* gA = A + (size_t)(row0 + rA) * 1024 + cA * 8;
    ushort_t* lA = As + tid * 8;
    const int i0 = tid, i1 = 256 + tid;
    const int rB0 = i0 >> 2, cB0 = (i0 & 3) ^ (rB0 & 3);
    const int rB1 = i1 >> 2, cB1 = (i1 & 3) ^ (rB1 & 3);
    const ushort_t* gB0 = Bt + (size_t)(col0 + rB0) * 1024 + cB0 * 8;
    const ushort_t* gB1 = Bt + (size_t)(col0 + rB1) * 1024 + cB1 * 8;
    ushort_t* lB0 = Bs + i0 * 8;  ushort_t* lB1 = Bs + i1 * 8;

    const int sa_off = (quad ^ (l16 & 3)) * 8;

    for (int k0 = 0; k0 < 1024; k0 += 32) {
        __syncthreads();
        gload16(gA + k0, lA);
        gload16(gB0 + k0, lB0);
        gload16(gB1 + k0, lB1);
        __syncthreads();

        short8 af[2], bf[4];
#pragma unroll
        for (int i = 0; i < 2; ++i)
            af[i] = *(const short8*)(As + (wm * 32 + i * 16 + l16) * 32 + sa_off);
#pragma unroll
        for (int j = 0; j < 4; ++j)
            bf[j] = *(const short8*)(Bs + (wn * 64 + j * 16 + l16) * 32 + sa_off);
#pragma unroll
        for (int i = 0; i < 2; ++i)
#pragma unroll
            for (int j = 0; j < 4; ++j)
                acc[i][j] = mfma16x32(af[i], bf[j], acc[i][j]);
    }

#pragma unroll
    for (int i = 0; i < 2; ++i)
#pragma unroll
        for (int j = 0; j < 4; ++j) {
            const int c = col0 + wn * 64 + j * 16 + l16;
            const float bv = bias[c];
#pragma unroll
            for (int rr = 0; rr < 4; ++rr) {
                const int r = row0 + wm * 32 + i * 16 + quad * 4 + rr;
                Dout[(size_t)r * 1024 + c] = acc[i][j][rr] + bv;
            }
        }
}

// ---------------------------------------------------------------------------
// Attention: R7's VERIFIED numerics at 2x wave parallelism.
// Grid 512 = 32 bh (head-major, XCD = blk%8) x 16 q-tiles of 128 rows;
// 8 waves x 16 q-rows each (512 threads). R7 post-mortem: kernel is
// occupancy-bound at 2 waves/SIMD (~65% SIMD idle); K-frag/V-frag LDS reads
// are per-wave constants (q-independent), so 8x16 instead of 4x32 doubles
// waves/SIMD (2->4) at identical total MFMA/VALU/HBM cost; only LDS reads
// double (~19% of step budget -> ~38%, affordable). Per-thread staging is
// exactly 1 gload16 per tensor per half. All fragment maps are R5/R7's
// verified ones with the u-subtile dimension removed.
// ---------------------------------------------------------------------------
__global__ __launch_bounds__(512, 2) void attn64q(
    const ushort_t* __restrict__ Q, const ushort_t* __restrict__ K,
    const ushort_t* __restrict__ Vt, ushort_t* __restrict__ Out)
{
    __shared__ __align__(16) ushort_t Ks[2][2][64 * 64];  // [buf][half][kcol][d]
    __shared__ __align__(16) ushort_t Vs[2][2][64 * 64];  // [buf][half][d][kcol]

    const int tid = threadIdx.x;
    const int lane = tid & 63, wid = tid >> 6;   // 8 waves
    const int quad = lane >> 4, l16 = lane & 15;
    const int blk = blockIdx.x;
    const int bh = blk & 31;          // head-major: XCD = blk%8 = bh%8
    const int q0 = (blk >> 5) << 7;   // 128 q-rows per block

    const ushort_t* Qh = Q + (size_t)bh * (2048 * 64);
    const ushort_t* Kh = K + (size_t)bh * (2048 * 64);
    const ushort_t* Vh = Vt + (size_t)bh * (64 * 2048);

    // Q fragments (B-operand: n=qrow=l16, k=8*quad+j), one 16-row subtile
    const int qr = q0 + wid * 16 + l16;
    const short8 qf0 = *(const short8*)(Qh + (size_t)qr * 64 + quad * 8);
    const short8 qf1 = *(const short8*)(Qh + (size_t)qr * 64 + 32 + quad * 8);

    floatx4 o_acc[4], lsum = zero4();
#pragma unroll
    for (int d = 0; d < 4; ++d) o_acc[d] = zero4();

    // staging: ONE 16B slot per thread per tensor per half (512 thr = 512 slots).
    // slot tid: kr = tid>>3 (0..63), kc = (tid&7)^(kr&7).
    const int kr = tid >> 3, kc = (tid & 7) ^ (kr & 7);
    const ushort_t* gK0 = Kh + (size_t)kr * 64 + kc * 8;
    const ushort_t* gV0 = Vh + (size_t)kr * 2048 + kc * 8;

    const int l7 = l16 & 7;
    const int q2 = quad >> 1, q1 = (quad & 1) * 4;

    union { uint_t u4[4]; short8 s; } onep;
    onep.u4[0] = onep.u4[1] = onep.u4[2] = onep.u4[3] = 0x3f803f80u;  // bf16 1.0
    const short8 ones = onep.s;

    // STAGE: both 64-kcol halves of buffer pp for K-tile starting at kto.
#define STAGE(pp, kto) do {                                                  \
        _Pragma("unroll")                                                    \
        for (int hf_ = 0; hf_ < 2; ++hf_) {                                  \
            gload16(gK0 + (size_t)(kto) * 64 + hf_ * 4096,                   \
                    &Ks[pp][hf_][tid * 8]);                                  \
            gload16(gV0 + (kto) + hf_ * 64,                                  \
                    &Vs[pp][hf_][tid * 8]);                                  \
        }                                                                    \
    } while (0)

    STAGE(0, 0);
    for (int it = 0; it < 16; ++it) {
        const int p = it & 1;
        __syncthreads();                            // drains prev STAGE (vmcnt0)
        if (it < 15) STAGE(p ^ 1, (it + 1) * 128);  // overlaps with compute below

#pragma unroll
        for (int hf = 0; hf < 2; ++hf) {
            const ushort_t* ksp = &Ks[p][hf][0];
            const ushort_t* vsp = &Vs[p][hf][0];

            // S^T tiles: A = K-frag (m=kcol), B = Q-frag (regs)
            floatx4 sa[4];
#pragma unroll
            for (int g = 0; g < 4; ++g) {
                const int row = g * 16 + l16;  // kcol
                const short8 kf0 = *(const short8*)(ksp + row * 64 + ((quad ^ l7) * 8));
                const short8 kf1 = *(const short8*)(ksp + row * 64 + (((quad + 4) ^ l7) * 8));
                floatx4 t0 = mfma16x32(kf0, qf0, zero4());
                sa[g] = mfma16x32(kf1, qf1, t0);
            }

            // softmax + pack two g-blocks per K=32 PV MFMA
#pragma unroll
            for (int G = 0; G < 2; ++G) {
                uint_t ub[8];
#pragma unroll
                for (int t = 0; t < 8; ++t) {
                    const int g = G * 2 + (t >> 2), r = t & 3;
                    const float e = __builtin_amdgcn_exp2f(fminf(sa[g][r], 80.f));
                    ub[t] = __float_as_uint(e);
                }
                union { uint_t u4[4]; short8 s; } pc;
                // one v_perm per pair: dst = {hi16(ub[2w+1]), hi16(ub[2w])}
                pc.u4[0] = __builtin_amdgcn_perm(ub[1], ub[0], 0x07060302u);
                pc.u4[1] = __builtin_amdgcn_perm(ub[3], ub[2], 0x07060302u);
                pc.u4[2] = __builtin_amdgcn_perm(ub[5], ub[4], 0x07060302u);
                pc.u4[3] = __builtin_amdgcn_perm(ub[7], ub[6], 0x07060302u);
                const short8 pf = pc.s;
                // denominator via MFMA: sums the exact truncated P used in PV
                lsum = mfma16x32(pf, ones, lsum);

                const int ch0 = ((4 * G + q2) ^ l7) * 8;
                const int ch1 = ((4 * G + 2 + q2) ^ l7) * 8;
#pragma unroll
                for (int db = 0; db < 4; ++db) {
                    const int vbase = (db * 16 + l16) * 64 + q1;
                    const uint2 v0 = *(const uint2*)(vsp + vbase + ch0);
                    const uint2 v1 = *(const uint2*)(vsp + vbase + ch1);
                    union { uint_t u4[4]; short8 s; } vc;
                    vc.u4[0] = v0.x; vc.u4[1] = v0.y; vc.u4[2] = v1.x; vc.u4[3] = v1.y;
                    o_acc[db] = mfma16x32(pf, vc.s, o_acc[db]);
                }
            }
        }
    }
#undef STAGE

    // epilogue: lsum[r] is the denom of qrow quad*4+r (same C/D row map as
    // o_acc) — no shuffles needed.
    const int b = bh >> 4, hh = bh & 15;
    const int s0 = q0 + wid * 16 + quad * 4;
#pragma unroll
    for (int r = 0; r < 4; ++r) {
        const float inv = 1.f / lsum[r];
#pragma unroll
        for (int db = 0; db < 4; ++db) {
            const float v = o_acc[db][r] * inv;
            Out[(size_t)(b * 2048 + s0 + r) * 1024 + hh * 64 + db * 16 + l16] = f2bf(v);
        }
    }
}

// ---------------------------------------------------------------------------
// Launch (attn grid 512 = 32 bh x 16 q-tiles of 128 rows, 512 threads).
//  big (>=64MiB): WT@0 Qb@8M Kb@16M Vb@24M Qp@32M Kp@40M Vtp@48M An@56M
//  small (40MiB): WT@0 buf1@8M buf2@16M Qp@24M Kp@32M
// ---------------------------------------------------------------------------
extern "C" void kernel_launch(void* const* d_in, const int* in_sizes, int n_in,
                              void* d_out, int out_size, void* d_ws, size_t ws_size,
                              hipStream_t stream) {
    const float* queries = (const float*)d_in[0];
    const float* keys    = (const float*)d_in[1];
    const float* values  = (const float*)d_in[2];
    const float* Wq = (const float*)d_in[3];
    const float* bq = (const float*)d_in[4];
    const float* Wk = (const float*)d_in[5];
    const float* bk = (const float*)d_in[6];
    const float* Wv = (const float*)d_in[7];
    const float* bv = (const float*)d_in[8];
    const float* Wo = (const float*)d_in[9];
    const float* bo = (const float*)d_in[10];
    float* out = (float*)d_out;

    char* ws = (char*)d_ws;
    const size_t MB = 1024 * 1024;
    ushort_t* WT = (ushort_t*)(ws);
    const ushort_t* WoT = WT + 3 * 1048576;
    dim3 tb(256);
    dim3 ta(512);

    transpose_w<<<dim3(256, 4), tb, 0, stream>>>(Wq, Wk, Wv, Wo, WT);

    if (ws_size >= 64 * MB) {
        ushort_t* Qb  = (ushort_t*)(ws + 8 * MB);
        ushort_t* Kb  = (ushort_t*)(ws + 16 * MB);
        ushort_t* Vb  = (ushort_t*)(ws + 24 * MB);
        ushort_t* Qp  = (ushort_t*)(ws + 32 * MB);
        ushort_t* Kp  = (ushort_t*)(ws + 40 * MB);
        ushort_t* Vtp = (ushort_t*)(ws + 48 * MB);
        ushort_t* An  = (ushort_t*)(ws + 56 * MB);
        cvt_bf16<<<dim3(6144), tb, 0, stream>>>(queries, keys, values, Qb, Kb, Vb);
        gemm_bt<<<dim3(8, 32, 3), tb, 0, stream>>>(Qb, Kb, Vb, WT,
            bq, bk, bv, Qp, Kp, Vtp, 0);
        attn64q<<<dim3(512), ta, 0, stream>>>(Qp, Kp, Vtp, An);
        gemm64<<<dim3(8, 64), tb, 0, stream>>>(An, WoT, bo, out);
    } else {
        ushort_t* buf1 = (ushort_t*)(ws + 8 * MB);
        ushort_t* buf2 = (ushort_t*)(ws + 16 * MB);
        ushort_t* Qp   = (ushort_t*)(ws + 24 * MB);
        ushort_t* Kp   = (ushort_t*)(ws + 32 * MB);
        cvt_bf16<<<dim3(4096), tb, 0, stream>>>(queries, keys, keys, buf1, buf2, buf2);
        gemm_bt<<<dim3(8, 32, 2), tb, 0, stream>>>(buf1, buf2, buf2, WT,
            bq, bk, bk, Qp, Kp, Kp, 0);
        cvt_bf16<<<dim3(2048), tb, 0, stream>>>(values, values, values, buf1, buf1, buf1);
        gemm_bt<<<dim3(8, 32, 1), tb, 0, stream>>>(buf1, buf1, buf1, WT,
            bv, bv, bv, buf2, buf2, buf2, 2);   // mode 2: V -> Vtp = buf2
        attn64q<<<dim3(512), ta, 0, stream>>>(Qp, Kp, buf2, buf1);
        gemm64<<<dim3(8, 64), tb, 0, stream>>>(buf1, WoT, bo, out);
    }
}